// Round 7
// baseline (325.566 us; speedup 1.0000x reference)
//
#include <hip/hip_runtime.h>
#include <hip/hip_bf16.h>

// Graph attention: B=8,H=8,N=1024,d=128. fp32 in/out, bf16 MFMA compute.
// R16: structural rework of the 32x32x16 kernel fixing BOTH standing issues:
//  (a) steady-state VGPR spill at the (512,4) 128-reg budget (R13-R15):
//      Q is prepacked to bf16 (Qp in ws) and STREAMED per-iteration from
//      global (loop-invariant addrs -> L1/L2-hot). qf's 32 persistent regs
//      become transient; peak demand ~105 < 128.
//  (b) 4-way LDS bank conflicts (5.2M/dispatch since R11): K/V/Ps row strides
//      were all ==0 mod 32 banks (256B/128B rows), so bank=f(chunk) only and
//      32 lanes / 8 chunks = 4-way. Fix: ODD-dword padded strides
//      (Kt 130, Vt 66, Ps 70 bf16) -> bank=(odd*row+4*chunk)%32 is a full
//      permutation over l31 -> 2-way max (free). No XOR swizzles needed.
//  Padded LDS is incompatible with global_load_lds (linear dest), so K/V are
//  reg-staged T14-style: global->regs at iter top (latency spans the whole
//  iteration), ds_write K' after bar2 (Kt dead, overlaps PV), V' after bar3.
//  3 barriers/iter, compiler-managed waits. LDS 51.5 KB -> 2 blocks/CU,
//  16 waves/CU. setprio on MFMA clusters kept.
// Fallbacks: full path needs ~50.5 MB ws (adds Qp); else R14 mid path
// (33.7 MB, measured 89.6us); else R8 fallback.

typedef __bf16 bf16x8 __attribute__((ext_vector_type(8)));
typedef float  f32x4  __attribute__((ext_vector_type(4)));
typedef float  f32x16 __attribute__((ext_vector_type(16)));
typedef unsigned int u32;
typedef u32 u32x4 __attribute__((ext_vector_type(4)));

#define NSEQ 1024
#define DH   128
#define BN   64
#define NKT  16
#define TILE_ELEMS (BN * DH)           // 8192 bf16 = 16 KB
#define C1 0.1803368801111244f         // 0.125 * log2(e)
#define C2 11.5415603271110070f        // 8 * log2(e)
#define KLD 130                        // Kt row stride (65 dw, odd)
#define VLD 66                         // Vt row stride (33 dw, odd)
#define PLD 70                         // Ps row stride (35 dw, odd)

__device__ __forceinline__ float f4get(const float4& v, int c) {
    return (c == 0) ? v.x : (c == 1) ? v.y : (c == 2) ? v.z : v.w;
}

__device__ __forceinline__ void gload_lds16(const void* g, void* l) {
    __builtin_amdgcn_global_load_lds(
        (const __attribute__((address_space(1))) u32*)g,
        (__attribute__((address_space(3))) u32*)l, 16, 0, 0);
}

__device__ __forceinline__ bf16x8 cvt8(const float* src) {
    float4 a = *(const float4*)src;
    float4 b = *(const float4*)(src + 4);
    bf16x8 w;
    w[0]=(__bf16)a.x; w[1]=(__bf16)a.y; w[2]=(__bf16)a.z; w[3]=(__bf16)a.w;
    w[4]=(__bf16)b.x; w[5]=(__bf16)b.y; w[6]=(__bf16)b.z; w[7]=(__bf16)b.w;
    return w;
}

// ============ full-path pre-pass: plain bf16 K/V/Q tiles + adj bits =========
__global__ __launch_bounds__(256)
void prepack_full(const float* __restrict__ K, const float* __restrict__ V,
                  const float* __restrict__ Qf,
                  __bf16* __restrict__ Kws, __bf16* __restrict__ Vws,
                  __bf16* __restrict__ Qp, u32* __restrict__ adjc,
                  const int* __restrict__ adj)
{
    const int tid = threadIdx.x;
    const int id  = blockIdx.x;

    if (id >= 1152) {
        // Q pack: flat fp32 -> bf16, 512 blocks x 256 thr x 64 elems
        const size_t e0 = (size_t)(id - 1152) * 16384 + tid * 8;
        #pragma unroll
        for (int i = 0; i < 8; ++i) {
            const size_t e = e0 + (size_t)i * 2048;
            *(bf16x8*)(Qp + e) = cvt8(Qf + e);
        }
        return;
    }
    if (id >= 1024) {
        // adjc[kv][rg32] u32: bit j = adj[rg32*32 + j][kv] > 0.
        const int idx  = id - 1024;          // 0..127
        const int rg32 = idx & 31;
        const int kv   = (idx >> 5) * 256 + tid;
        u32 w = 0;
        #pragma unroll
        for (int j = 0; j < 32; ++j)
            w |= (u32)(adj[(size_t)(rg32 * 32 + j) * NSEQ + kv] > 0) << j;
        adjc[(size_t)kv * 32 + rg32] = w;
        return;
    }

    const size_t gbase = (size_t)(id >> 4) * NSEQ * DH + (size_t)(id & 15) * BN * DH;
    __bf16* ko = Kws + (size_t)id * TILE_ELEMS;
    __bf16* vo = Vws + (size_t)id * TILE_ELEMS;

    // K tile 64x128 plain pack (no swizzle)
    #pragma unroll
    for (int p = 0; p < 4; ++p) {
        const int r = p * 16 + (tid >> 4);
        const int c = tid & 15;
        *(bf16x8*)(ko + r * DH + c * 8) = cvt8(K + gbase + (size_t)r * DH + c * 8);
    }
    // V tile transposed -> [d][kv] 128x64 plain
    {
        const int vkvb = tid >> 5;         // 0..7
        const int vdb  = tid & 31;         // 4 d each
        float4 vr[8];
        #pragma unroll
        for (int rr = 0; rr < 8; ++rr)
            vr[rr] = *(const float4*)(V + gbase + (size_t)(vkvb * 8 + rr) * DH + vdb * 4);
        #pragma unroll
        for (int c = 0; c < 4; ++c) {
            const int d = vdb * 4 + c;
            bf16x8 w;
            #pragma unroll
            for (int j = 0; j < 8; ++j) w[j] = (__bf16)f4get(vr[j], c);
            *(bf16x8*)(vo + d * BN + vkvb * 8) = w;
        }
    }
}

// ============ full-path hot kernel: T14-staged, conflict-free LDS ===========
__global__ __launch_bounds__(512, 4)
void attn_full(const __bf16* __restrict__ Qp, const __bf16* __restrict__ Kws,
               const __bf16* __restrict__ Vws, const u32* __restrict__ adjc,
               float* __restrict__ out)
{
    __shared__ __attribute__((aligned(16))) __bf16 Kt[64 * KLD];   // 16.25 KB
    __shared__ __attribute__((aligned(16))) __bf16 Vt[128 * VLD];  // 16.5 KB
    __shared__ __attribute__((aligned(16))) __bf16 Ps[128 * PLD];  // 17.5 KB

    const int tid  = threadIdx.x;
    const int wave = tid >> 6;            // 0..7
    const int lane = tid & 63;
    const int l31  = lane & 31;
    const int hi   = lane >> 5;           // 0/1
    const int rowg = wave >> 1;           // 0..3: q-rows rowg*32..+31
    const int colg = wave & 1;            // 0..1: kv cols (S), d-half (PV)

    const int id = blockIdx.x;            // XCD swizzle (R6-proven)
    const int bh = (id & 7) * 8 + ((id >> 3) & 7);
    const int q0 = (id >> 6) * 128;
    const size_t tile0 = (size_t)(bh * NKT) * TILE_ELEMS;

    // ---- staging coords: K 64x16 chunks, V 128x8 chunks, 2 chunks/thread ----
    const int ksr = 8 * wave + (lane >> 3);        // K row
    const int ksc = lane & 7;                      // K chunks ksc, ksc+8
    const int vsr = 16 * wave + (lane & 15);       // V row (d)
    const int vsc = 2 * (lane >> 4);               // V chunks vsc, vsc+1
    const __bf16* kg = Kws + tile0 + ksr * DH + ksc * 8;
    const __bf16* vg = Vws + tile0 + vsr * BN + vsc * 8;
    __bf16* kd = &Kt[ksr * KLD + ksc * 8];
    __bf16* vd = &Vt[vsr * VLD + vsc * 8];

    // ---- compute-phase pointers (all strides odd-dword -> conflict-free) ----
    const __bf16* qp = Qp + ((size_t)bh << 17)
                     + ((size_t)(q0 + rowg * 32 + l31) << 7) + hi * 8;
    const __bf16* kr = &Kt[(colg * 32 + l31) * KLD + hi * 8];
    const __bf16* pr = &Ps[(rowg * 32 + l31) * PLD + hi * 8];
    const __bf16* vr = &Vt[(colg * 64 + l31) * VLD + hi * 8];
    __bf16* pw = &Ps[(rowg * 32 + 4 * hi) * PLD + colg * 32 + l31];
    const u32* ap = adjc + (size_t)(colg * 32 + l31) * 32 + (q0 >> 5) + rowg;

    f32x16 o0, o1;
    #pragma unroll
    for (int i = 0; i < 16; ++i) { o0[i] = 0.f; o1[i] = 0.f; }
    float rs = 0.f;

    // ---- prologue: stage tile 0 (global->reg->LDS) ----
    {
        bf16x8 ka = *(const bf16x8*)(kg);
        bf16x8 kb = *(const bf16x8*)(kg + 64);
        bf16x8 va = *(const bf16x8*)(vg);
        bf16x8 vb = *(const bf16x8*)(vg + 8);
        *(bf16x8*)kd = ka;  *(bf16x8*)(kd + 64) = kb;
        *(bf16x8*)vd = va;  *(bf16x8*)(vd + 8) = vb;
    }

    for (int kt = 0; kt < NKT; ++kt) {
        // ---- bar1: staged ds_writes visible -> Kt/Vt ready ----
        __builtin_amdgcn_sched_barrier(0);
        asm volatile("s_waitcnt lgkmcnt(0)" ::: "memory");
        __builtin_amdgcn_s_barrier();
        __builtin_amdgcn_sched_barrier(0);

        const u32 am = ap[kt * 2048];

        // ---- issue next-tile loads to REGS (latency spans the iteration) ----
        const int st = (kt < NKT - 1) ? (kt + 1) : (NKT - 1);  // last: dead reload
        const __bf16* kgs = kg + (size_t)st * TILE_ELEMS;
        const __bf16* vgs = vg + (size_t)st * TILE_ELEMS;
        bf16x8 ka = *(const bf16x8*)(kgs);
        bf16x8 kb = *(const bf16x8*)(kgs + 64);
        bf16x8 va = *(const bf16x8*)(vgs);
        bf16x8 vb = *(const bf16x8*)(vgs + 8);
        __builtin_amdgcn_sched_barrier(0);

        // ---- S = Q K^T: Q streamed from global, K from padded LDS ----
        f32x16 s;
        #pragma unroll
        for (int i = 0; i < 16; ++i) s[i] = 0.f;
        __builtin_amdgcn_s_setprio(1);
        #pragma unroll
        for (int ks = 0; ks < 8; ++ks) {
            bf16x8 qv = *(const bf16x8*)(qp + ks * 16);
            bf16x8 kf = *(const bf16x8*)(kr + ks * 16);
            s = __builtin_amdgcn_mfma_f32_32x32x16_bf16(qv, kf, s, 0, 0, 0);
            if (ks == 3) __builtin_amdgcn_sched_barrier(0);  // cap Q in-flight
        }
        __builtin_amdgcn_s_setprio(0);

        // ---- masked softmax; plain Ps writes (stride 70, no swizzle) ----
        {
            const u32 m2 = am >> (hi * 4);
            #pragma unroll
            for (int reg = 0; reg < 16; ++reg) {
                const int rlo = (reg & 3) + 8 * (reg >> 2);    // compile-time
                float p = exp2f(__builtin_fmaf(s[reg], C1, -C2));
                p = ((m2 >> rlo) & 1u) ? p : 0.f;
                pw[rlo * PLD] = (__bf16)p;
            }
        }

        // ---- bar2: Ps visible; all waves past S -> Kt dead ----
        __builtin_amdgcn_sched_barrier(0);
        asm volatile("s_waitcnt lgkmcnt(0)" ::: "memory");
        __builtin_amdgcn_s_barrier();
        __builtin_amdgcn_sched_barrier(0);

        // ---- write K' now (overlaps PV; Kt not read again until next S) ----
        *(bf16x8*)kd = ka;
        *(bf16x8*)(kd + 64) = kb;
        __builtin_amdgcn_sched_barrier(0);

        // ---- O += P V: P and V from padded LDS; rs from pa fragments ----
        __builtin_amdgcn_s_setprio(1);
        #pragma unroll
        for (int kstep = 0; kstep < 4; ++kstep) {
            bf16x8 pa = *(const bf16x8*)(pr + kstep * 16);
            bf16x8 v0 = *(const bf16x8*)(vr + kstep * 16);
            bf16x8 v1 = *(const bf16x8*)(vr + 32 * VLD + kstep * 16);
            o0 = __builtin_amdgcn_mfma_f32_32x32x16_bf16(pa, v0, o0, 0, 0, 0);
            o1 = __builtin_amdgcn_mfma_f32_32x32x16_bf16(pa, v1, o1, 0, 0, 0);
            u32x4 pu = __builtin_bit_cast(u32x4, pa);
            #pragma unroll
            for (int w = 0; w < 4; ++w) {
                const u32 d = pu[w];
                rs += __uint_as_float(d << 16);
                rs += __uint_as_float(d & 0xffff0000u);
            }
        }
        __builtin_amdgcn_s_setprio(0);

        // ---- bar3: all PV done -> Vt dead; then write V' ----
        __builtin_amdgcn_sched_barrier(0);
        __builtin_amdgcn_s_barrier();
        __builtin_amdgcn_sched_barrier(0);
        *(bf16x8*)vd = va;
        *(bf16x8*)(vd + 8) = vb;
        // next iter's bar1 lgkmcnt(0) covers these writes
    }

    // ---- epilogue: complete row sums, broadcast via LDS (Ps dead), store ----
    rs += __shfl_xor(rs, 32);             // full sum of row rowg*32 + l31
    __syncthreads();
    float* Ls = (float*)&Ps[0];
    if (lane < 32 && colg == 0)
        Ls[rowg * 32 + l31] = rs;
    __syncthreads();
    const size_t base = (size_t)bh * NSEQ * DH;
    #pragma unroll
    for (int reg = 0; reg < 16; ++reg) {
        const int row = rowg * 32 + (reg & 3) + 8 * (reg >> 2) + 4 * hi;
        const float linv = 1.0f / fmaxf(Ls[row], 1e-30f);
        float* orow = out + base + (size_t)(q0 + row) * DH + colg * 64 + l31;
        orow[0]  = o0[reg] * linv;
        orow[32] = o1[reg] * linv;
    }
}

// ============ mid path (R14, measured 89.6us): swizzled tiles + gload_lds ===
__global__ __launch_bounds__(256)
void prepack_mid(const float* __restrict__ K, const float* __restrict__ V,
                 __bf16* __restrict__ Kws, __bf16* __restrict__ Vws,
                 u32* __restrict__ adjc, const int* __restrict__ adj)
{
    const int tid = threadIdx.x;
    const int id  = blockIdx.x;

    if (id >= 1024) {
        const int idx  = id - 1024;
        const int rg32 = idx & 31;
        const int kv   = (idx >> 5) * 256 + tid;
        u32 w = 0;
        #pragma unroll
        for (int j = 0; j < 32; ++j)
            w |= (u32)(adj[(size_t)(rg32 * 32 + j) * NSEQ + kv] > 0) << j;
        adjc[(size_t)kv * 32 + rg32] = w;
        return;
    }

    const size_t gbase = (size_t)(id >> 4) * NSEQ * DH + (size_t)(id & 15) * BN * DH;
    __bf16* ko = Kws + (size_t)id * TILE_ELEMS;
    __bf16* vo = Vws + (size_t)id * TILE_ELEMS;

    #pragma unroll
    for (int p = 0; p < 4; ++p) {
        const int r = p * 16 + (tid >> 4);
        const int c = tid & 15;
        const int cs = (c & 8) | ((c ^ (r & 7)) & 7);
        *(bf16x8*)(ko + r * DH + cs * 8) = cvt8(K + gbase + (size_t)r * DH + c * 8);
    }
    {
        const int vkvb = tid >> 5;
        const int vdb  = tid & 31;
        float4 vr[8];
        #pragma unroll
        for (int rr = 0; rr < 8; ++rr)
            vr[rr] = *(const float4*)(V + gbase + (size_t)(vkvb * 8 + rr) * DH + vdb * 4);
        #pragma unroll
        for (int c = 0; c < 4; ++c) {
            const int d = vdb * 4 + c;
            bf16x8 w;
            #pragma unroll
            for (int j = 0; j < 8; ++j) w[j] = (__bf16)f4get(vr[j], c);
            const int cs = vkvb ^ (d & 7);
            *(bf16x8*)(vo + d * BN + cs * 8) = w;
        }
    }
}

__global__ __launch_bounds__(512, 4)
void attn_mid(const float* __restrict__ Q, const __bf16* __restrict__ Kws,
              const __bf16* __restrict__ Vws, const u32* __restrict__ adjc,
              float* __restrict__ out)
{
    __shared__ __attribute__((aligned(16))) __bf16 Kt[2][TILE_ELEMS];
    __shared__ __attribute__((aligned(16))) __bf16 Vt[TILE_ELEMS];
    __shared__ __attribute__((aligned(16))) __bf16 Ps[128 * BN];

    const int tid  = threadIdx.x;
    const int wave = tid >> 6;
    const int lane = tid & 63;
    const int l31  = lane & 31;
    const int hi   = lane >> 5;
    const int l7   = lane & 7;
    const int rowg = wave >> 1;
    const int colg = wave & 1;

    const int id = blockIdx.x;
    const int bh = (id & 7) * 8 + ((id >> 3) & 7);
    const int q0 = (id >> 6) * 128;
    const size_t base  = (size_t)bh * NSEQ * DH;
    const size_t tile0 = (size_t)(bh * NKT) * TILE_ELEMS;

    bf16x8 qf[8];
    {
        const float* qrowp = Q + base + (size_t)(q0 + rowg * 32 + l31) * DH + hi * 8;
        #pragma unroll
        for (int ks = 0; ks < 8; ++ks) qf[ks] = cvt8(qrowp + ks * 16);
    }

    const size_t ab = (size_t)(colg * 32 + l31) * 32 + (q0 >> 5) + rowg;
    const int kbase = (colg * 32 + l31) * DH * 2;

    f32x16 o0, o1;
    #pragma unroll
    for (int i = 0; i < 16; ++i) { o0[i] = 0.f; o1[i] = 0.f; }
    float rs = 0.f;

    #pragma unroll
    for (int j = 0; j < 2; ++j) {
        const int off = wave * 1024 + j * 512;
        gload_lds16(Kws + tile0 + off + lane * 8, &Kt[0][off]);
    }

    for (int kt = 0; kt < NKT; ++kt) {
        __builtin_amdgcn_sched_barrier(0);
        asm volatile("s_waitcnt vmcnt(0)" ::: "memory");
        __builtin_amdgcn_sched_barrier(0);
        __builtin_amdgcn_s_barrier();
        __builtin_amdgcn_sched_barrier(0);

        const u32 am = adjc[ab + (size_t)kt * 2048];
        __builtin_amdgcn_sched_barrier(0);

        {
            const __bf16* vtile = Vws + tile0 + (size_t)kt * TILE_ELEMS;
            #pragma unroll
            for (int j = 0; j < 2; ++j) {
                const int off = wave * 1024 + j * 512;
                gload_lds16(vtile + off + lane * 8, &Vt[off]);
            }
        }
        __builtin_amdgcn_sched_barrier(0);
        {
            const int ktn = (kt + 1) & (NKT - 1);
            const __bf16* ktile = Kws + tile0 + (size_t)ktn * TILE_ELEMS;
            __bf16* kdst = &Kt[ktn & 1][0];
            #pragma unroll
            for (int j = 0; j < 2; ++j) {
                const int off = wave * 1024 + j * 512;
                gload_lds16(ktile + off + lane * 8, kdst + off);
            }
        }
        __builtin_amdgcn_sched_barrier(0);

        const __bf16* Kc = &Kt[kt & 1][0];
        f32x16 s;
        #pragma unroll
        for (int i = 0; i < 16; ++i) s[i] = 0.f;
        __builtin_amdgcn_s_setprio(1);
        #pragma unroll
        for (int ks = 0; ks < 8; ++ks) {
            const int c  = ks * 2 + hi;
            const int cs = (c & 8) | ((c ^ l7) & 7);
            bf16x8 bfr = *(const bf16x8*)((const char*)Kc + kbase + cs * 16);
            s = __builtin_amdgcn_mfma_f32_32x32x16_bf16(qf[ks], bfr, s, 0, 0, 0);
        }
        __builtin_amdgcn_s_setprio(0);

        {
            const u32 m2 = am >> (hi * 4);
            const int chunk0 = colg * 4 + (l31 >> 3);
            const int wbase  = (rowg * 32 + 4 * hi) * BN + l7;
            #pragma unroll
            for (int reg = 0; reg < 16; ++reg) {
                const int rlo = (reg & 3) + 8 * (reg >> 2);
                float p = exp2f(s[reg] * C1 - C2);
                p = ((m2 >> rlo) & 1u) ? p : 0.f;
                const int swc = chunk0 ^ ((reg & 3) | (hi << 2));
                Ps[wbase + rlo * BN + swc * 8] = (__bf16)p;
            }
        }

        __builtin_amdgcn_sched_barrier(0);
        asm volatile("s_waitcnt vmcnt(2) lgkmcnt(0)" ::: "memory");
        __builtin_amdgcn_sched_barrier(0);
        __builtin_amdgcn_s_barrier();
        __builtin_amdgcn_sched_barrier(0);

        __builtin_amdgcn_s_setprio(1);
        #pragma unroll
        for (int kstep = 0; kstep < 4; ++kstep) {
            const int chs = (kstep * 2 + hi) ^ l7;
            bf16x8 pa = *(const bf16x8*)(&Ps[(rowg * 32 + l31) * BN + chs * 8]);
            bf16x8 vf0 = *(const bf16x8*)(&Vt[(l31)      * BN + chs * 8 + colg * 64 * BN]);
            o0 = __builtin_amdgcn_mfma_f32_32x32x16_bf16(pa, vf0, o0, 0, 0, 0);
            bf16x8 vf1 = *(const bf16x8*)(&Vt[(32 + l31) * BN + chs * 8 + colg * 64 * BN]);
            o1 = __builtin_amdgcn_mfma_f32_32x32x16_bf16(pa, vf1, o1, 0, 0, 0);
            u32x4 pu = __builtin_bit_cast(u32x4, pa);
            #pragma unroll
            for (int w = 0; w < 4; ++w) {
                const u32 d = pu[w];
                rs += __uint_as_float(d << 16);
                rs += __uint_as_float(d & 0xffff0000u);
            }
        }
        __builtin_amdgcn_s_setprio(0);
    }

    rs += __shfl_xor(rs, 32);
    __syncthreads();
    float* Ls = (float*)&Vt[0];
    if (lane < 32 && colg == 0)
        Ls[rowg * 32 + l31] = rs;
    __syncthreads();
    #pragma unroll
    for (int reg = 0; reg < 16; ++reg) {
        const int row = rowg * 32 + (reg & 3) + 8 * (reg >> 2) + 4 * hi;
        const float linv = 1.0f / fmaxf(Ls[row], 1e-30f);
        float* orow = out + base + (size_t)(q0 + row) * DH + colg * 64 + l31;
        orow[0]  = o0[reg] * linv;
        orow[32] = o1[reg] * linv;
    }
}

// ============ fallback (R8-proven) if ws too small ==========================
#define KS_STRIDE 136
#define VT_STRIDE 64
#define PS_STRIDE 72

__global__ __launch_bounds__(256, 4)
void attn_fallback(const float* __restrict__ Q, const float* __restrict__ K,
                   const float* __restrict__ V, const int* __restrict__ adj,
                   float* __restrict__ out)
{
    __shared__ __attribute__((aligned(16))) __bf16 KsP[BN * KS_STRIDE];
    __shared__ __attribute__((aligned(16))) __bf16 Vts[DH * VT_STRIDE];
    const int tid = threadIdx.x;
    const int wave = tid >> 6, lane = tid & 63, n16 = lane & 15, quad = lane >> 4;
    const int id = blockIdx.x;
    const int bh = (id & 7) * 8 + ((id >> 3) & 7);
    const int q0 = (id >> 6) * 64;
    const size_t base = (size_t)bh * NSEQ * DH;
    const int rp = tid >> 4, kcol = (tid & 15) * 8, db = tid & 31, kvb = tid >> 5;
    bf16x8 qf[4];
    #pragma unroll
    for (int ks = 0; ks < 4; ++ks)
        qf[ks] = cvt8(Q + base + (size_t)(q0 + wave * 16 + n16) * DH + ks * 32 + quad * 8);
    f32x4 o[8];
    #pragma unroll
    for (int i = 0; i < 8; ++i) o[i] = (f32x4){0.f, 0.f, 0.f, 0.f};
    float lp[4] = {0.f, 0.f, 0.f, 0.f};
    const int qrow = q0 + wave * 16 + quad * 4;
    for (int kt = 0; kt < NKT; ++kt) {
        const int kv0 = kt * BN;
        __syncthreads();
        #pragma unroll
        for (int it = 0; it < 4; ++it) {
            int row = 16 * it + rp;
            *(bf16x8*)(&KsP[row * KS_STRIDE + kcol]) =
                cvt8(K + base + (size_t)(kv0 + row) * DH + kcol);
        }
        {
            float4 vreg[8];
            #pragma unroll
            for (int rr = 0; rr < 8; ++rr)
                vreg[rr] = *(const float4*)(V + base + (size_t)(kv0 + kvb * 8 + rr) * DH + db * 4);
            #pragma unroll
            for (int c = 0; c < 4; ++c) {
                bf16x8 w;
                #pragma unroll
                for (int j = 0; j < 8; ++j) w[j] = (__bf16)f4get(vreg[j], c);
                int d = db * 4 + c, s = (d ^ (d >> 3)) & 7;
                *(bf16x8*)(&Vts[d * VT_STRIDE + ((kvb ^ s) << 3)]) = w;
            }
        }
        __syncthreads();
        int am[4][4];
        #pragma unroll
        for (int i = 0; i < 4; ++i)
            #pragma unroll
            for (int t = 0; t < 4; ++t)
                am[i][t] = adj[(size_t)(qrow + i) * NSEQ + kv0 + t * 16 + n16];
        float sc[4][4];
        #pragma unroll
        for (int t = 0; t < 4; ++t) {
            f32x4 acc = (f32x4){0.f, 0.f, 0.f, 0.f};
            #pragma unroll
            for (int ks = 0; ks < 4; ++ks) {
                bf16x8 bfr = *(const bf16x8*)(&KsP[(t * 16 + n16) * KS_STRIDE + ks * 32 + quad * 8]);
                acc = __builtin_amdgcn_mfma_f32_16x16x32_bf16(qf[ks], bfr, acc, 0, 0, 0);
            }
            #pragma unroll
            for (int i = 0; i < 4; ++i) sc[t][i] = acc[i];
        }
        __syncthreads();
        #pragma unroll
        for (int i = 0; i < 4; ++i) {
            const int prow = wave * 16 + quad * 4 + i;
            float rowsum = 0.f;
            #pragma unroll
            for (int t = 0; t < 4; ++t) {
                float p = exp2f(sc[t][i] * C1 - C2);
                p = (am[i][t] > 0) ? p : 0.f;
                rowsum += p;
                KsP[prow * PS_STRIDE + t * 16 + n16] = (__bf16)p;
            }
            lp[i] += rowsum;
        }
        #pragma unroll
        for (int ks = 0; ks < 2; ++ks) {
            bf16x8 pf = *(const bf16x8*)(&KsP[(wave * 16 + n16) * PS_STRIDE + ks * 32 + quad * 8]);
            #pragma unroll
            for (int nt = 0; nt < 8; ++nt) {
                int d = nt * 16 + n16, s = (d ^ (d >> 3)) & 7, kvbr = ks * 4 + quad;
                bf16x8 vf = *(const bf16x8*)(&Vts[d * VT_STRIDE + ((kvbr ^ s) << 3)]);
                o[nt] = __builtin_amdgcn_mfma_f32_16x16x32_bf16(pf, vf, o[nt], 0, 0, 0);
            }
        }
    }
    float linv[4];
    #pragma unroll
    for (int i = 0; i < 4; ++i) {
        float ls = lp[i];
        ls += __shfl_xor(ls, 1); ls += __shfl_xor(ls, 2);
        ls += __shfl_xor(ls, 4); ls += __shfl_xor(ls, 8);
        linv[i] = 1.0f / fmaxf(ls, 1e-30f);
    }
    #pragma unroll
    for (int nt = 0; nt < 8; ++nt)
        #pragma unroll
        for (int i = 0; i < 4; ++i)
            out[base + (size_t)(qrow + i) * DH + nt * 16 + n16] = o[nt][i] * linv[i];
}

extern "C" void kernel_launch(void* const* d_in, const int* in_sizes, int n_in,
                              void* d_out, int out_size, void* d_ws, size_t ws_size,
                              hipStream_t stream) {
    const float* Q   = (const float*)d_in[0];
    const float* K   = (const float*)d_in[1];
    const float* V   = (const float*)d_in[2];
    const int*   adj = (const int*)d_in[3];
    float* out = (float*)d_out;
    const size_t nKV  = (size_t)2 * 64 * NKT * TILE_ELEMS * sizeof(__bf16); // 33.55 MB
    const size_t nQ   = (size_t)64 * NSEQ * DH * sizeof(__bf16);            // 16.78 MB
    const size_t nAdj = (size_t)NSEQ * 32 * sizeof(u32);                    // 128 KB
    if (ws_size >= nKV + nQ + nAdj) {
        __bf16* Kws = (__bf16*)d_ws;
        __bf16* Vws = Kws + (size_t)64 * NKT * TILE_ELEMS;
        __bf16* Qp  = Vws + (size_t)64 * NKT * TILE_ELEMS;
        u32* adjc = (u32*)(Qp + (size_t)64 * NSEQ * DH);
        prepack_full<<<1664, 256, 0, stream>>>(K, V, Q, Kws, Vws, Qp, adjc, adj);
        attn_full<<<512, 512, 0, stream>>>(Qp, Kws, Vws, adjc, out);
    } else if (ws_size >= nKV + nAdj) {
        __bf16* Kws = (__bf16*)d_ws;
        __bf16* Vws = Kws + (size_t)64 * NKT * TILE_ELEMS;
        u32* adjc = (u32*)(Vws + (size_t)64 * NKT * TILE_ELEMS);
        prepack_mid<<<1152, 256, 0, stream>>>(K, V, Kws, Vws, adjc, adj);
        attn_mid<<<512, 512, 0, stream>>>(Q, Kws, Vws, adjc, out);
    } else {
        attn_fallback<<<1024, 256, 0, stream>>>(Q, K, V, adj, out);
    }
}